// Round 10
// baseline (119.359 us; speedup 1.0000x reference)
//
#include <hip/hip_runtime.h>
#include <math.h>

// FrequencyAttention: QF = (TWF.qT).W^T ; d_out = TWI.(U.OVW^T)^T + b_out.
// Split-bf16 MFMA (hi/lo, 3-term). W/U consumed fp32-direct with in-register
// split; OVW fused into GEMM C's fragment loader. 8 stages.

typedef __bf16 bf16x8 __attribute__((ext_vector_type(8)));
typedef float  f32x4  __attribute__((ext_vector_type(4)));

__device__ __forceinline__ unsigned short f2bf(float x) {
    unsigned u = __builtin_bit_cast(unsigned, x);
    u = (u + 0x7fffu + ((u >> 16) & 1u)) >> 16;   // RTN-even
    return (unsigned short)u;
}
__device__ __forceinline__ float bf2f(unsigned short h) {
    return __builtin_bit_cast(float, ((unsigned)h) << 16);
}
__device__ __forceinline__ void split2(float x, unsigned short& h, unsigned short& l) {
    h = f2bf(x);
    l = f2bf(x - bf2f(h));
}
__device__ __forceinline__ void split8(const float4& a0, const float4& a1,
                                       bf16x8& hv, bf16x8& lv) {
    float v[8] = {a0.x, a0.y, a0.z, a0.w, a1.x, a1.y, a1.z, a1.w};
#pragma unroll
    for (int j = 0; j < 8; j++) {
        unsigned short h, l; split2(v[j], h, l);
        hv[j] = __builtin_bit_cast(__bf16, h);
        lv[j] = __builtin_bit_cast(__bf16, l);
    }
}

__device__ __forceinline__ void gload16(const void* g, void* l) {
    __builtin_amdgcn_global_load_lds(
        (const __attribute__((address_space(1))) unsigned int*)g,
        (__attribute__((address_space(3))) unsigned int*)l,
        16, 0, 0);
}

// ---- prep: twiddles + query transpose/split ---------------------------------
__global__ __launch_bounds__(256) void prep(
    const float* __restrict__ q,
    unsigned short* __restrict__ qTh, unsigned short* __restrict__ qTl,
    unsigned short* __restrict__ TWFh, unsigned short* __restrict__ TWFl,
    unsigned short* __restrict__ TWIh, unsigned short* __restrict__ TWIl)
{
    __shared__ float T[64][65];
    int bid = blockIdx.x, tid = threadIdx.x;
    if (bid < 256) {                       // twiddles: 65536 = 64f x 1024s
        int idx = bid * 256 + tid;
        int f = idx >> 10, s = idx & 1023;
        float th = (float)((f * s) & 1023) * (6.283185307179586f / 1024.0f);
        float sn, c;
        sincosf(th, &sn, &c);
        unsigned short ch, cl, sh, sl;
        split2(c, ch, cl); split2(sn, sh, sl);
        TWFh[(2 * f) * 1024 + s] = ch;     TWFl[(2 * f) * 1024 + s] = cl;
        TWFh[(2 * f + 1) * 1024 + s] = sh; TWFl[(2 * f + 1) * 1024 + s] = sl;
        TWIh[s * 128 + 2 * f] = ch;        TWIl[s * 128 + 2 * f] = cl;
        TWIh[s * 128 + 2 * f + 1] = sh;    TWIl[s * 128 + 2 * f + 1] = sl;
    } else {                               // transpose+split query, 1024 blocks
        int t = bid - 256;
        int k0 = (t & 15) * 64, s0 = ((t >> 4) & 15) * 64, b = t >> 8;
        const float* src = q + ((size_t)b * 1024 + s0) * 1024 + k0;
        int tr = tid >> 4, tc4 = (tid & 15) * 4;
#pragma unroll
        for (int rs = 0; rs < 4; rs++) {
            int r = rs * 16 + tr;
            float4 v = *(const float4*)&src[(size_t)r * 1024 + tc4];
            T[tc4 + 0][r] = v.x; T[tc4 + 1][r] = v.y;
            T[tc4 + 2][r] = v.z; T[tc4 + 3][r] = v.w;
        }
        __syncthreads();
        unsigned short* dh = qTh + ((size_t)b * 1024 + k0) * 1024 + s0;
        unsigned short* dl = qTl + ((size_t)b * 1024 + k0) * 1024 + s0;
#pragma unroll
        for (int rs = 0; rs < 4; rs++) {
            int kk = rs * 16 + tr;
            ushort4 hh, ll;
            split2(T[kk][tc4 + 0], hh.x, ll.x);
            split2(T[kk][tc4 + 1], hh.y, ll.y);
            split2(T[kk][tc4 + 2], hh.z, ll.z);
            split2(T[kk][tc4 + 3], hh.w, ll.w);
            *(ushort4*)&dh[(size_t)kk * 1024 + tc4] = hh;
            *(ushort4*)&dl[(size_t)kk * 1024 + tc4] = ll;
        }
    }
}

// ---- 64x64-tile split-bf16 MFMA NT GEMM -------------------------------------
// AMODE: 0 = bf16 hi/lo via LDS, 1 = fp32 direct (in-reg split)
// BOPM : 0 = bf16 hi/lo via LDS, 1 = fp32 direct, 2 = fused OVW = attn*wv*QFv
// KS>1: write fp32 partials P[z][M][N]. BMODE: 0 none, 1 col-bias, 2 DC-row bias.
template<int KS, int BMODE, int AMODE, int BOPM>
__global__ __launch_bounds__(256, 4) void mfma64(
    const unsigned short* __restrict__ Ah, const unsigned short* __restrict__ Al,
    const float* __restrict__ Af32, int lda, long bsA,
    const unsigned short* __restrict__ Bh, const unsigned short* __restrict__ Bl,
    const float* __restrict__ Bf32, int ldb, long bsB,
    const float* __restrict__ attn, const float* __restrict__ wvf,
    float* __restrict__ Cf, unsigned short* __restrict__ Ch, unsigned short* __restrict__ Cl,
    int ldc, long bsC, float* __restrict__ Pf, const float* __restrict__ bias, int K)
{
    __shared__ unsigned short smem[8192];     // up to Ah|Al|Bh|Bl 64x32, 4KB each
    const int tid = threadIdx.x, lane = tid & 63, w = tid >> 6;
    const int wm = w >> 1, wn = w & 1;
    const int m0 = blockIdx.y * 64, n0 = blockIdx.x * 64;
    const int la = lane & 15, kg = lane >> 4;
    int bz, ks;
    if constexpr (KS > 1) { bz = blockIdx.z / KS; ks = blockIdx.z % KS; }
    else                  { bz = blockIdx.z; ks = 0; }
    const int Kc = K / KS;

    const unsigned short *pAh, *pAl, *pBh, *pBl;
    if constexpr (AMODE == 0) {
        pAh = Ah + (long)bz * bsA + (size_t)(m0 + w * 16 + la) * lda + ks * Kc + kg * 8;
        pAl = Al + (long)bz * bsA + (size_t)(m0 + w * 16 + la) * lda + ks * Kc + kg * 8;
    }
    if constexpr (BOPM == 0) {
        pBh = Bh + (long)bz * bsB + (size_t)(n0 + w * 16 + la) * ldb + ks * Kc + kg * 8;
        pBl = Bl + (long)bz * bsB + (size_t)(n0 + w * 16 + la) * ldb + ks * Kc + kg * 8;
    }
    constexpr bool USE_LDS = (AMODE == 0) || (BOPM == 0);

    f32x4 acc[2][2] = {};
    for (int kt = 0; kt < Kc; kt += 32) {
        const int kcur = ks * Kc + kt;
        if constexpr (USE_LDS) {
            if constexpr (AMODE == 0) {
                gload16(pAh, &smem[w * 512]);
                gload16(pAl, &smem[2048 + w * 512]);
                pAh += 32; pAl += 32;
            }
            if constexpr (BOPM == 0) {
                gload16(pBh, &smem[4096 + w * 512]);
                gload16(pBl, &smem[6144 + w * 512]);
                pBh += 32; pBl += 32;
            }
            __syncthreads();
        }
        bf16x8 fah[2], fal[2], fbh[2], fbl[2];
#pragma unroll
        for (int i = 0; i < 2; i++) {
            if constexpr (AMODE == 0) {
                fah[i] = *reinterpret_cast<const bf16x8*>(&smem[(wm * 2 + i) * 512 + lane * 8]);
                fal[i] = *reinterpret_cast<const bf16x8*>(&smem[2048 + (wm * 2 + i) * 512 + lane * 8]);
            } else {
                int row = m0 + (wm * 2 + i) * 16 + la;
                const float* p = Af32 + (size_t)row * lda + kcur + kg * 8;
                float4 a0 = *(const float4*)p, a1 = *(const float4*)(p + 4);
                split8(a0, a1, fah[i], fal[i]);
            }
        }
#pragma unroll
        for (int i = 0; i < 2; i++) {
            if constexpr (BOPM == 0) {
                fbh[i] = *reinterpret_cast<const bf16x8*>(&smem[4096 + (wn * 2 + i) * 512 + lane * 8]);
                fbl[i] = *reinterpret_cast<const bf16x8*>(&smem[6144 + (wn * 2 + i) * 512 + lane * 8]);
            } else if constexpr (BOPM == 1) {
                int row = n0 + (wn * 2 + i) * 16 + la;
                const float* p = Bf32 + (size_t)row * ldb + kcur + kg * 8;
                float4 b0 = *(const float4*)p, b1 = *(const float4*)(p + 4);
                split8(b0, b1, fbh[i], fbl[i]);
            } else {   // BOPM == 2: OVW[(b,f2)][ch] = attn*wv*QFv on the fly
                int f2 = n0 + (wn * 2 + i) * 16 + la;
                int f = f2 >> 1, h = kcur >> 6;
                const float* qp = Bf32 + (size_t)(bz * 128 + f2) * 3072 + 2048 + kcur + kg * 8;
                float4 q0 = *(const float4*)qp, q1 = *(const float4*)(qp + 4);
                const float* wp = wvf + h * 4096 + f * 64 + (kcur & 63) + kg * 8;
                float4 w0 = *(const float4*)wp, w1 = *(const float4*)(wp + 4);
                float a = attn[(bz * 16 + h) * 64 + f];
                float4 v0, v1;
                v0.x = a * q0.x * w0.x; v0.y = a * q0.y * w0.y;
                v0.z = a * q0.z * w0.z; v0.w = a * q0.w * w0.w;
                v1.x = a * q1.x * w1.x; v1.y = a * q1.y * w1.y;
                v1.z = a * q1.z * w1.z; v1.w = a * q1.w * w1.w;
                split8(v0, v1, fbh[i], fbl[i]);
            }
        }
#pragma unroll
        for (int j = 0; j < 2; j++)
#pragma unroll
            for (int i = 0; i < 2; i++) {
                acc[i][j] = __builtin_amdgcn_mfma_f32_16x16x32_bf16(fah[i], fbh[j], acc[i][j], 0, 0, 0);
                acc[i][j] = __builtin_amdgcn_mfma_f32_16x16x32_bf16(fal[i], fbh[j], acc[i][j], 0, 0, 0);
                acc[i][j] = __builtin_amdgcn_mfma_f32_16x16x32_bf16(fah[i], fbl[j], acc[i][j], 0, 0, 0);
            }
        if constexpr (USE_LDS) __syncthreads();
    }

    const int r0 = (lane >> 4) * 4, cl = lane & 15;
    if constexpr (KS > 1) {
        const int M = gridDim.y * 64, N = gridDim.x * 64;
        float* Pb = Pf + (long)blockIdx.z * M * N;
#pragma unroll
        for (int i = 0; i < 2; i++)
#pragma unroll
            for (int j = 0; j < 2; j++)
#pragma unroll
                for (int r = 0; r < 4; r++)
                    Pb[(long)(m0 + wm * 32 + i * 16 + r0 + r) * N + (n0 + wn * 32 + j * 16 + cl)]
                        = acc[i][j][r];
    } else {
        float* Cfb = Cf + (long)bz * bsC;
#pragma unroll
        for (int i = 0; i < 2; i++)
#pragma unroll
            for (int j = 0; j < 2; j++) {
                int gr0 = m0 + wm * 32 + i * 16 + r0;
                int gc  = n0 + wn * 32 + j * 16 + cl;
                float bn = (BMODE == 1) ? bias[gc] : 0.f;
#pragma unroll
                for (int r = 0; r < 4; r++) {
                    int gr = gr0 + r;
                    float v = acc[i][j][r] + bn;
                    if (BMODE == 2 && (gr & 127) == 0) v += 1024.0f * bias[gc];
                    Cfb[(size_t)gr * ldc + gc] = v;
                }
            }
    }
}

// ---- split-K reduce -> bf16 hi/lo -------------------------------------------
template<int KS>
__global__ void reduce_k(const float* __restrict__ P,
                         unsigned short* __restrict__ Ch, unsigned short* __restrict__ Cl,
                         int mn4bits, int total4)
{
    int e = blockIdx.x * 256 + threadIdx.x;
    if (e >= total4) return;
    int bz = e >> mn4bits, rem = e & ((1 << mn4bits) - 1);
    const float4* P4 = (const float4*)P;
    float4 s = P4[((long)(bz * KS) << mn4bits) + rem];
#pragma unroll
    for (int k = 1; k < KS; k++) {
        float4 t = P4[((long)(bz * KS + k) << mn4bits) + rem];
        s.x += t.x; s.y += t.y; s.z += t.z; s.w += t.w;
    }
    long o4 = ((long)bz << mn4bits) + rem;
    ushort4 hh, ll;
    split2(s.x, hh.x, ll.x); split2(s.y, hh.y, ll.y);
    split2(s.z, hh.z, ll.z); split2(s.w, hh.w, ll.w);
    ((ushort4*)Ch)[o4] = hh;
    ((ushort4*)Cl)[o4] = ll;
}

// ---- scores (fp32) + 1024-wide softmax -> attn[bh][64] ----------------------
__global__ void score_k(const float* __restrict__ QF,
                        const float* __restrict__ fq, const float* __restrict__ fk,
                        float* __restrict__ attnW) {
    int bh = blockIdx.x, b = bh >> 4, h = bh & 15;
    const float* QFb = QF + (size_t)b * 393216;     // [128 f2][3072 ch]
    const float* wq = fq + (size_t)h * 4096;
    const float* wk = fk + (size_t)h * 4096;
    __shared__ float red[256];
    int tid = threadIdx.x;
    int f = tid & 63, dg = tid >> 6;
    int cq = h * 64;
    float p = 0.f;
#pragma unroll
    for (int i = 0; i < 16; i++) {
        int d = dg * 16 + i;
        float w2 = wq[f * 64 + d] * wk[f * 64 + d];
        p += w2 * (QFb[(2 * f) * 3072 + cq + d]     * QFb[(2 * f) * 3072 + 1024 + cq + d]
                 + QFb[(2 * f + 1) * 3072 + cq + d] * QFb[(2 * f + 1) * 3072 + 1024 + cq + d]);
    }
    red[tid] = p;
    __syncthreads();
    if (tid < 64) {
        float s = red[tid] + red[tid + 64] + red[tid + 128] + red[tid + 192];
        float mx = s;
        for (int m = 1; m < 64; m <<= 1) mx = fmaxf(mx, __shfl_xor(mx, m));
        mx = fmaxf(mx, 0.0f);                   // padded zero scores join the max
        float e = expf(s - mx);
        float sum = e;
        for (int m = 1; m < 64; m <<= 1) sum += __shfl_xor(sum, m);
        sum += 960.0f * expf(-mx);              // the S-M zero-score entries
        attnW[bh * 64 + tid] = e / sum;
    }
}

extern "C" void kernel_launch(void* const* d_in, const int* in_sizes, int n_in,
                              void* d_out, int out_size, void* d_ws, size_t ws_size,
                              hipStream_t stream) {
    const float* query  = (const float*)d_in[0];
    const float* w_qkv  = (const float*)d_in[1];
    const float* b_qkv  = (const float*)d_in[2];
    const float* w_out  = (const float*)d_in[3];
    const float* b_out  = (const float*)d_in[4];
    const float* freq_q = (const float*)d_in[5];
    const float* freq_k = (const float*)d_in[6];
    const float* freq_v = (const float*)d_in[7];

    char* W = (char*)d_ws;
    unsigned short* qTh  = (unsigned short*)(W);                  // [4][1024][1024]
    unsigned short* qTl  = (unsigned short*)(W + 8388608);
    unsigned short* TWFh = (unsigned short*)(W + 16777216);       // [128][1024]
    unsigned short* TWFl = (unsigned short*)(W + 17039360);
    unsigned short* TWIh = (unsigned short*)(W + 17301504);       // [1024][128]
    unsigned short* TWIl = (unsigned short*)(W + 17563648);
    unsigned short* TWQh = (unsigned short*)(W + 17825792);       // [512][1024]
    unsigned short* TWQl = (unsigned short*)(W + 18874368);
    float*          QF   = (float*)        (W + 19922944);        // [512][3072] fp32
    unsigned short* POVh = (unsigned short*)(W + 26214400);       // [4][1024][128]
    unsigned short* POVl = (unsigned short*)(W + 27262976);
    float*          attnW= (float*)        (W + 28311552);        // [64][64]
    float*          P_A  = (float*)        (W + 28327936);        // [16][128][1024]
    float*          P_C  = (float*)        (W + 36716544);        // [16][1024][128]
                                                                  // end 45105152 B

    prep<<<1280, 256, 0, stream>>>(query, qTh, qTl, TWFh, TWFl, TWIh, TWIl);

    // A: TWQ[(b,f2)][k] = sum_s TWF[f2][s]*qT[b][k][s]   (split-K=4 -> partials)
    mfma64<4, 0, 0, 0><<<dim3(16, 2, 16), 256, 0, stream>>>(
        TWFh, TWFl, nullptr, 1024, 0, qTh, qTl, nullptr, 1024, 1048576,
        nullptr, nullptr, nullptr, nullptr, nullptr, 0, 0, P_A, nullptr, 1024);
    reduce_k<4><<<512, 256, 0, stream>>>(P_A, TWQh, TWQl, 15, 131072);

    // B: QF[(b,f2)][c] = sum_k TWQ[(b,f2)][k]*w_qkv[c][k]  (+1024*b_qkv at DC rows)
    mfma64<1, 2, 0, 1><<<dim3(48, 8, 1), 256, 0, stream>>>(
        TWQh, TWQl, nullptr, 1024, 0, nullptr, nullptr, w_qkv, 1024, 0,
        nullptr, nullptr, QF, nullptr, nullptr, 3072, 0, nullptr, b_qkv, 1024);

    // scores -> softmax(1024-wide) -> attn
    score_k<<<64, 256, 0, stream>>>(QF, freq_q, freq_k, attnW);

    // C: POV[b][n][f2] = sum_ch w_out[n][ch]*(attn*wv*QFv)[(b,f2)][ch]  (split-K=4)
    mfma64<4, 0, 1, 2><<<dim3(2, 16, 16), 256, 0, stream>>>(
        nullptr, nullptr, w_out, 1024, 0, nullptr, nullptr, QF, 3072, 0,
        attnW, freq_v, nullptr, nullptr, nullptr, 0, 0, P_C, nullptr, 1024);
    reduce_k<4><<<512, 256, 0, stream>>>(P_C, POVh, POVl, 15, 131072);

    // D: d_out[b][s][n] = sum_f2 TWI[s][f2]*POV[b][n][f2] + b_out[n]
    mfma64<1, 1, 0, 0><<<dim3(16, 16, 4), 256, 0, stream>>>(
        TWIh, TWIl, nullptr, 128, 0, POVh, POVl, nullptr, 128, 131072,
        nullptr, nullptr, (float*)d_out, nullptr, nullptr, 1024, 1048576,
        nullptr, b_out, 128);
}

// Round 11
// 97.895 us; speedup vs baseline: 1.2193x; 1.2193x over previous
//
#include <hip/hip_runtime.h>
#include <math.h>

// FrequencyAttention: QF = (TWF.qT).W^T ; d_out = TWI.(U.OVW^T)^T + b_out.
// Split-bf16 MFMA (hi/lo, 3-term) on 64x64 tiles; split-K + fp32 reduce for
// the small-grid GEMMs (deterministic, no atomics). Scores/softmax fp32.
// R11 = R9 structure + split-K=2 on GEMM B (DC bias folded into ks==0 partial).

typedef __bf16 bf16x8 __attribute__((ext_vector_type(8)));
typedef float  f32x4  __attribute__((ext_vector_type(4)));

__device__ __forceinline__ unsigned short f2bf(float x) {
    unsigned u = __builtin_bit_cast(unsigned, x);
    u = (u + 0x7fffu + ((u >> 16) & 1u)) >> 16;   // RTN-even
    return (unsigned short)u;
}
__device__ __forceinline__ float bf2f(unsigned short h) {
    return __builtin_bit_cast(float, ((unsigned)h) << 16);
}
__device__ __forceinline__ void split2(float x, unsigned short& h, unsigned short& l) {
    h = f2bf(x);
    l = f2bf(x - bf2f(h));
}

__device__ __forceinline__ void gload16(const void* g, void* l) {
    __builtin_amdgcn_global_load_lds(
        (const __attribute__((address_space(1))) unsigned int*)g,
        (__attribute__((address_space(3))) unsigned int*)l,
        16, 0, 0);
}

// ---- fused prep: twiddles + weight split + query transpose/split ------------
__global__ __launch_bounds__(256) void prep(
    const float* __restrict__ q, const float* __restrict__ wq, const float* __restrict__ wo,
    unsigned short* __restrict__ qTh, unsigned short* __restrict__ qTl,
    unsigned short* __restrict__ Wh, unsigned short* __restrict__ Wl,
    unsigned short* __restrict__ Uh, unsigned short* __restrict__ Ul,
    unsigned short* __restrict__ TWFh, unsigned short* __restrict__ TWFl,
    unsigned short* __restrict__ TWIh, unsigned short* __restrict__ TWIl)
{
    __shared__ float T[64][65];
    int bid = blockIdx.x, tid = threadIdx.x;
    if (bid < 256) {                       // twiddles: 65536 = 64f x 1024s
        int idx = bid * 256 + tid;
        int f = idx >> 10, s = idx & 1023;
        float th = (float)((f * s) & 1023) * (6.283185307179586f / 1024.0f);
        float sn, c;
        sincosf(th, &sn, &c);
        unsigned short ch, cl, sh, sl;
        split2(c, ch, cl); split2(sn, sh, sl);
        TWFh[(2 * f) * 1024 + s] = ch;     TWFl[(2 * f) * 1024 + s] = cl;
        TWFh[(2 * f + 1) * 1024 + s] = sh; TWFl[(2 * f + 1) * 1024 + s] = sl;
        TWIh[s * 128 + 2 * f] = ch;        TWIl[s * 128 + 2 * f] = cl;
        TWIh[s * 128 + 2 * f + 1] = sh;    TWIl[s * 128 + 2 * f + 1] = sl;
    } else if (bid < 4352) {               // split w_qkv, w_out (float4 idx)
        long i = (long)(bid - 256) * 256 + tid;
        const float* src; unsigned short *dh, *dl; long off;
        if (i < 786432) { src = wq; dh = Wh; dl = Wl; off = i; }
        else            { src = wo; dh = Uh; dl = Ul; off = i - 786432; }
        float4 v = ((const float4*)src)[off];
        ushort4 hh, ll;
        split2(v.x, hh.x, ll.x); split2(v.y, hh.y, ll.y);
        split2(v.z, hh.z, ll.z); split2(v.w, hh.w, ll.w);
        ((ushort4*)dh)[off] = hh;
        ((ushort4*)dl)[off] = ll;
    } else {                               // transpose+split query
        int t = bid - 4352;                // 1024 blocks
        int k0 = (t & 15) * 64, s0 = ((t >> 4) & 15) * 64, b = t >> 8;
        const float* src = q + ((size_t)b * 1024 + s0) * 1024 + k0;
        int tr = tid >> 4, tc4 = (tid & 15) * 4;
#pragma unroll
        for (int rs = 0; rs < 4; rs++) {
            int r = rs * 16 + tr;
            float4 v = *(const float4*)&src[(size_t)r * 1024 + tc4];
            T[tc4 + 0][r] = v.x; T[tc4 + 1][r] = v.y;
            T[tc4 + 2][r] = v.z; T[tc4 + 3][r] = v.w;
        }
        __syncthreads();
        unsigned short* dh = qTh + ((size_t)b * 1024 + k0) * 1024 + s0;
        unsigned short* dl = qTl + ((size_t)b * 1024 + k0) * 1024 + s0;
#pragma unroll
        for (int rs = 0; rs < 4; rs++) {
            int kk = rs * 16 + tr;
            ushort4 hh, ll;
            split2(T[kk][tc4 + 0], hh.x, ll.x);
            split2(T[kk][tc4 + 1], hh.y, ll.y);
            split2(T[kk][tc4 + 2], hh.z, ll.z);
            split2(T[kk][tc4 + 3], hh.w, ll.w);
            *(ushort4*)&dh[(size_t)kk * 1024 + tc4] = hh;
            *(ushort4*)&dl[(size_t)kk * 1024 + tc4] = ll;
        }
    }
}

// ---- 64x64-tile split-bf16 MFMA NT GEMM, optional split-K partial output ----
// C[m][n] = sum_k A[m][k]*B[n][k]. KS>1: write fp32 partial at Pf + z*bsC
// (bsC = padded slice stride in floats). BMODE: 0 none, 1 col-bias b[n],
// 2 DC-row bias (+1024*b[n] where (row&127)==0; in partials only at ks==0).
template<int KS, int BMODE, bool SPLIT>
__global__ __launch_bounds__(256, 4) void mfma64(
    const unsigned short* __restrict__ Ah, const unsigned short* __restrict__ Al,
    int lda, long bsA,
    const unsigned short* __restrict__ Bh, const unsigned short* __restrict__ Bl,
    int ldb, long bsB,
    float* __restrict__ Cf, unsigned short* __restrict__ Ch, unsigned short* __restrict__ Cl,
    int ldc, long bsC,
    float* __restrict__ Pf, const float* __restrict__ bias, int K)
{
    __shared__ unsigned short smem[8192];     // Ah|Al|Bh|Bl 64x32 tiles, 4KB each
    const int tid = threadIdx.x, lane = tid & 63, w = tid >> 6;
    const int wm = w >> 1, wn = w & 1;
    const int m0 = blockIdx.y * 64, n0 = blockIdx.x * 64;
    const int la = lane & 15, kg = lane >> 4;
    int bz, ks;
    if constexpr (KS > 1) { bz = blockIdx.z / KS; ks = blockIdx.z % KS; }
    else                  { bz = blockIdx.z; ks = 0; }
    const int Kc = K / KS;

    const unsigned short* pAh = Ah + (long)bz * bsA + (size_t)(m0 + w * 16 + la) * lda + ks * Kc + kg * 8;
    const unsigned short* pAl = Al + (long)bz * bsA + (size_t)(m0 + w * 16 + la) * lda + ks * Kc + kg * 8;
    const unsigned short* pBh = Bh + (long)bz * bsB + (size_t)(n0 + w * 16 + la) * ldb + ks * Kc + kg * 8;
    const unsigned short* pBl = Bl + (long)bz * bsB + (size_t)(n0 + w * 16 + la) * ldb + ks * Kc + kg * 8;

    f32x4 acc[2][2] = {};
    for (int kt = 0; kt < Kc; kt += 32) {
        gload16(pAh, &smem[w * 512]);
        gload16(pAl, &smem[2048 + w * 512]);
        gload16(pBh, &smem[4096 + w * 512]);
        gload16(pBl, &smem[6144 + w * 512]);
        pAh += 32; pAl += 32; pBh += 32; pBl += 32;
        __syncthreads();
        bf16x8 fah[2], fal[2], fbh[2], fbl[2];
#pragma unroll
        for (int i = 0; i < 2; i++) {
            fah[i] = *reinterpret_cast<const bf16x8*>(&smem[(wm * 2 + i) * 512 + lane * 8]);
            fal[i] = *reinterpret_cast<const bf16x8*>(&smem[2048 + (wm * 2 + i) * 512 + lane * 8]);
            fbh[i] = *reinterpret_cast<const bf16x8*>(&smem[4096 + (wn * 2 + i) * 512 + lane * 8]);
            fbl[i] = *reinterpret_cast<const bf16x8*>(&smem[6144 + (wn * 2 + i) * 512 + lane * 8]);
        }
#pragma unroll
        for (int j = 0; j < 2; j++)
#pragma unroll
            for (int i = 0; i < 2; i++) {
                acc[i][j] = __builtin_amdgcn_mfma_f32_16x16x32_bf16(fah[i], fbh[j], acc[i][j], 0, 0, 0);
                acc[i][j] = __builtin_amdgcn_mfma_f32_16x16x32_bf16(fal[i], fbh[j], acc[i][j], 0, 0, 0);
                acc[i][j] = __builtin_amdgcn_mfma_f32_16x16x32_bf16(fah[i], fbl[j], acc[i][j], 0, 0, 0);
            }
        __syncthreads();
    }

    const int r0 = (lane >> 4) * 4, cl = lane & 15;
    if constexpr (KS > 1) {
        const int N = gridDim.x * 64;
        float* Pb = Pf + (long)blockIdx.z * bsC;
#pragma unroll
        for (int i = 0; i < 2; i++)
#pragma unroll
            for (int j = 0; j < 2; j++) {
                int gr0 = m0 + wm * 32 + i * 16 + r0;
                int gc  = n0 + wn * 32 + j * 16 + cl;
#pragma unroll
                for (int r = 0; r < 4; r++) {
                    int gr = gr0 + r;
                    float v = acc[i][j][r];
                    if (BMODE == 2 && ks == 0 && (gr & 127) == 0)
                        v += 1024.0f * bias[gc];
                    Pb[(long)gr * N + gc] = v;
                }
            }
    } else {
        float* Cfb = Cf ? Cf + (long)bz * bsC : nullptr;
        unsigned short* Chb = Ch ? Ch + (long)bz * bsC : nullptr;
        unsigned short* Clb = Cl ? Cl + (long)bz * bsC : nullptr;
#pragma unroll
        for (int i = 0; i < 2; i++)
#pragma unroll
            for (int j = 0; j < 2; j++) {
                int gr0 = m0 + wm * 32 + i * 16 + r0;
                int gc  = n0 + wn * 32 + j * 16 + cl;
                float bn = (BMODE == 1) ? bias[gc] : 0.f;
#pragma unroll
                for (int r = 0; r < 4; r++) {
                    int gr = gr0 + r;
                    float v = acc[i][j][r] + bn;
                    if (BMODE == 2 && (gr & 127) == 0) v += 1024.0f * bias[gc];
                    size_t o = (size_t)gr * ldc + gc;
                    if (SPLIT) {
                        unsigned short hh, ll; split2(v, hh, ll);
                        Chb[o] = hh; Clb[o] = ll;
                    } else {
                        Cfb[o] = v;
                    }
                }
            }
    }
}

// ---- split-K reduce + epilogue (float4, pow2 slice strides via shifts) ------
template<int KS, bool SPLIT>
__global__ void reduce_k(const float* __restrict__ P,
                         float* __restrict__ Cf,
                         unsigned short* __restrict__ Ch, unsigned short* __restrict__ Cl,
                         int mn4bits, int total4)
{
    int e = blockIdx.x * 256 + threadIdx.x;
    if (e >= total4) return;
    int bz = e >> mn4bits, rem = e & ((1 << mn4bits) - 1);
    const float4* P4 = (const float4*)P;
    float4 s = P4[((long)(bz * KS) << mn4bits) + rem];
#pragma unroll
    for (int k = 1; k < KS; k++) {
        float4 t = P4[((long)(bz * KS + k) << mn4bits) + rem];
        s.x += t.x; s.y += t.y; s.z += t.z; s.w += t.w;
    }
    long o4 = ((long)bz << mn4bits) + rem;
    if (SPLIT) {
        ushort4 hh, ll;
        split2(s.x, hh.x, ll.x); split2(s.y, hh.y, ll.y);
        split2(s.z, hh.z, ll.z); split2(s.w, hh.w, ll.w);
        ((ushort4*)Ch)[o4] = hh;
        ((ushort4*)Cl)[o4] = ll;
    } else {
        ((float4*)Cf)[o4] = s;
    }
}

// ---- scores (fp32) + 1024-wide softmax -> attn[bh][64] -----------------------
__global__ void score_k(const float* __restrict__ QF,
                        const float* __restrict__ fq, const float* __restrict__ fk,
                        float* __restrict__ attnW) {
    int bh = blockIdx.x, b = bh >> 4, h = bh & 15;
    const float* QFb = QF + (size_t)b * 393216;     // [128 f2][3072 ch]
    const float* wq = fq + (size_t)h * 4096;
    const float* wk = fk + (size_t)h * 4096;
    __shared__ float red[256];
    int tid = threadIdx.x;
    int f = tid & 63, dg = tid >> 6;
    int cq = h * 64;
    float p = 0.f;
#pragma unroll
    for (int i = 0; i < 16; i++) {
        int d = dg * 16 + i;
        float w2 = wq[f * 64 + d] * wk[f * 64 + d];
        p += w2 * (QFb[(2 * f) * 3072 + cq + d]     * QFb[(2 * f) * 3072 + 1024 + cq + d]
                 + QFb[(2 * f + 1) * 3072 + cq + d] * QFb[(2 * f + 1) * 3072 + 1024 + cq + d]);
    }
    red[tid] = p;
    __syncthreads();
    if (tid < 64) {
        float s = red[tid] + red[tid + 64] + red[tid + 128] + red[tid + 192];
        float mx = s;
        for (int m = 1; m < 64; m <<= 1) mx = fmaxf(mx, __shfl_xor(mx, m));
        mx = fmaxf(mx, 0.0f);                   // padded zero scores join the max
        float e = expf(s - mx);
        float sum = e;
        for (int m = 1; m < 64; m <<= 1) sum += __shfl_xor(sum, m);
        sum += 960.0f * expf(-mx);              // the S-M zero-score entries
        attnW[bh * 64 + tid] = e / sum;
    }
}

// ---- OVW[b][f2][ch] = attn*wv*vf, split hi/lo (float4-wide elementwise) -----
__global__ void ov_k(const float* __restrict__ QF, const float* __restrict__ attnW,
                     const float* __restrict__ fv,
                     unsigned short* __restrict__ OVWh, unsigned short* __restrict__ OVWl) {
    int e = blockIdx.x * 256 + threadIdx.x;     // 131072 float4 = [4][128][1024]
    int b = e >> 15, rem = e & 32767;
    int f2 = rem >> 8, c4 = rem & 255;
    int ch = c4 * 4, h = ch >> 6, d = ch & 63;
    float4 v = *(const float4*)&QF[(size_t)(b * 128 + f2) * 3072 + 2048 + ch];
    float a = attnW[(b * 16 + h) * 64 + (f2 >> 1)];
    const float4 wvv = *(const float4*)&fv[h * 4096 + (f2 >> 1) * 64 + d];
    ushort4 hh, ll;
    split2(a * wvv.x * v.x, hh.x, ll.x);
    split2(a * wvv.y * v.y, hh.y, ll.y);
    split2(a * wvv.z * v.z, hh.z, ll.z);
    split2(a * wvv.w * v.w, hh.w, ll.w);
    long o4 = ((long)(b * 128 + f2) * 1024 + ch) >> 2;
    ((ushort4*)OVWh)[o4] = hh;
    ((ushort4*)OVWl)[o4] = ll;
}

extern "C" void kernel_launch(void* const* d_in, const int* in_sizes, int n_in,
                              void* d_out, int out_size, void* d_ws, size_t ws_size,
                              hipStream_t stream) {
    const float* query  = (const float*)d_in[0];
    const float* w_qkv  = (const float*)d_in[1];
    const float* b_qkv  = (const float*)d_in[2];
    const float* w_out  = (const float*)d_in[3];
    const float* b_out  = (const float*)d_in[4];
    const float* freq_q = (const float*)d_in[5];
    const float* freq_k = (const float*)d_in[6];
    const float* freq_v = (const float*)d_in[7];

    char* W = (char*)d_ws;
    unsigned short* qTh  = (unsigned short*)(W);                  // [4][1024][1024]
    unsigned short* qTl  = (unsigned short*)(W + 8388608);
    unsigned short* Wh   = (unsigned short*)(W + 16777216);       // [3072][1024]
    unsigned short* Wl   = (unsigned short*)(W + 23068672);
    unsigned short* Uh   = (unsigned short*)(W + 29360128);       // [1024][1024]
    unsigned short* Ul   = (unsigned short*)(W + 31457280);
    unsigned short* TWFh = (unsigned short*)(W + 33554432);       // [128][1024]
    unsigned short* TWFl = (unsigned short*)(W + 33816576);
    unsigned short* TWIh = (unsigned short*)(W + 34078720);       // [1024][128]
    unsigned short* TWIl = (unsigned short*)(W + 34340864);
    unsigned short* TWQh = (unsigned short*)(W + 34603008);       // [4][128][1024]
    unsigned short* TWQl = (unsigned short*)(W + 35651584);
    float*          QF   = (float*)        (W + 36700160);        // [512][3072] fp32
    unsigned short* OVWh = (unsigned short*)(W + 42991616);       // [4][128][1024]
    unsigned short* OVWl = (unsigned short*)(W + 44040192);
    unsigned short* POVh = (unsigned short*)(W + 45088768);       // [4][1024][128]
    unsigned short* POVl = (unsigned short*)(W + 46137344);
    float*          attnW= (float*)        (W + 47185920);        // [64][64]
    float*          P_A  = (float*)        (W + 47202304);        // [16][2^17] floats
    float*          P_C  = (float*)        (W + 55590912);        // [16][2^17] floats
    float*          P_B  = (float*)        (W + 63979520);        // [2][2^21] floats
                                                                  // end 80756736 B

    prep<<<5376, 256, 0, stream>>>(query, w_qkv, w_out, qTh, qTl, Wh, Wl, Uh, Ul,
                                   TWFh, TWFl, TWIh, TWIl);

    // A: TWQ[b][f2][k] = sum_s TWF[f2][s]*qT[b][k][s]   (split-K=4 -> partials)
    mfma64<4, 0, false><<<dim3(16, 2, 16), 256, 0, stream>>>(
        TWFh, TWFl, 1024, 0, qTh, qTl, 1024, 1048576,
        nullptr, nullptr, nullptr, 0, 131072, P_A, nullptr, 1024);
    reduce_k<4, true><<<512, 256, 0, stream>>>(P_A, nullptr, TWQh, TWQl, 15, 131072);

    // B: QF[(b,f2)][c] = sum_k TWQ[(b,f2)][k]*w_qkv[c][k]  (split-K=2,
    //    +1024*b_qkv at DC rows folded into ks==0 partial)
    mfma64<2, 2, false><<<dim3(48, 8, 2), 256, 0, stream>>>(
        TWQh, TWQl, 1024, 0, Wh, Wl, 1024, 0,
        nullptr, nullptr, nullptr, 0, 2097152, P_B, b_qkv, 1024);
    reduce_k<2, false><<<1536, 256, 0, stream>>>(P_B, QF, nullptr, nullptr, 19, 393216);

    // scores -> softmax(1024-wide) -> attn ; then OVW = attn*wv*vf (split)
    score_k<<<64, 256, 0, stream>>>(QF, freq_q, freq_k, attnW);
    ov_k<<<512, 256, 0, stream>>>(QF, attnW, freq_v, OVWh, OVWl);

    // C: POV[b][n][f2] = sum_ch w_out[n][ch]*OVW[b][f2][ch]  (split-K=4)
    mfma64<4, 0, false><<<dim3(2, 16, 16), 256, 0, stream>>>(
        Uh, Ul, 1024, 0, OVWh, OVWl, 1024, 131072,
        nullptr, nullptr, nullptr, 0, 131072, P_C, nullptr, 1024);
    reduce_k<4, true><<<512, 256, 0, stream>>>(P_C, nullptr, POVh, POVl, 15, 131072);

    // D: d_out[b][s][n] = sum_f2 TWI[s][f2]*POV[b][n][f2] + b_out[n]
    mfma64<1, 1, false><<<dim3(16, 16, 4), 256, 0, stream>>>(
        TWIh, TWIl, 128, 0, POVh, POVl, 128, 131072,
        (float*)d_out, nullptr, nullptr, 1024, 1048576, nullptr, b_out, 128);
}

// Round 12
// 96.483 us; speedup vs baseline: 1.2371x; 1.0146x over previous
//
#include <hip/hip_runtime.h>
#include <math.h>

// FrequencyAttention: QF = (TWF.qT).W^T ; d_out = TWI.(U.OVW^T)^T + b_out.
// Split-bf16 MFMA (hi/lo, 3-term) on 64x64 tiles; split-K + fp32 reduce.
// R12 = R11 + double-buffered LDS prefetch (2-phase) in mfma64: issue next
// K-tile's global_load_lds BEFORE computing current tile; 1 barrier/iter.

typedef __bf16 bf16x8 __attribute__((ext_vector_type(8)));
typedef float  f32x4  __attribute__((ext_vector_type(4)));

__device__ __forceinline__ unsigned short f2bf(float x) {
    unsigned u = __builtin_bit_cast(unsigned, x);
    u = (u + 0x7fffu + ((u >> 16) & 1u)) >> 16;   // RTN-even
    return (unsigned short)u;
}
__device__ __forceinline__ float bf2f(unsigned short h) {
    return __builtin_bit_cast(float, ((unsigned)h) << 16);
}
__device__ __forceinline__ void split2(float x, unsigned short& h, unsigned short& l) {
    h = f2bf(x);
    l = f2bf(x - bf2f(h));
}

__device__ __forceinline__ void gload16(const void* g, void* l) {
    __builtin_amdgcn_global_load_lds(
        (const __attribute__((address_space(1))) unsigned int*)g,
        (__attribute__((address_space(3))) unsigned int*)l,
        16, 0, 0);
}

// ---- fused prep: twiddles + weight split + query transpose/split ------------
__global__ __launch_bounds__(256) void prep(
    const float* __restrict__ q, const float* __restrict__ wq, const float* __restrict__ wo,
    unsigned short* __restrict__ qTh, unsigned short* __restrict__ qTl,
    unsigned short* __restrict__ Wh, unsigned short* __restrict__ Wl,
    unsigned short* __restrict__ Uh, unsigned short* __restrict__ Ul,
    unsigned short* __restrict__ TWFh, unsigned short* __restrict__ TWFl,
    unsigned short* __restrict__ TWIh, unsigned short* __restrict__ TWIl)
{
    __shared__ float T[64][65];
    int bid = blockIdx.x, tid = threadIdx.x;
    if (bid < 256) {                       // twiddles: 65536 = 64f x 1024s
        int idx = bid * 256 + tid;
        int f = idx >> 10, s = idx & 1023;
        float th = (float)((f * s) & 1023) * (6.283185307179586f / 1024.0f);
        float sn, c;
        sincosf(th, &sn, &c);
        unsigned short ch, cl, sh, sl;
        split2(c, ch, cl); split2(sn, sh, sl);
        TWFh[(2 * f) * 1024 + s] = ch;     TWFl[(2 * f) * 1024 + s] = cl;
        TWFh[(2 * f + 1) * 1024 + s] = sh; TWFl[(2 * f + 1) * 1024 + s] = sl;
        TWIh[s * 128 + 2 * f] = ch;        TWIl[s * 128 + 2 * f] = cl;
        TWIh[s * 128 + 2 * f + 1] = sh;    TWIl[s * 128 + 2 * f + 1] = sl;
    } else if (bid < 4352) {               // split w_qkv, w_out (float4 idx)
        long i = (long)(bid - 256) * 256 + tid;
        const float* src; unsigned short *dh, *dl; long off;
        if (i < 786432) { src = wq; dh = Wh; dl = Wl; off = i; }
        else            { src = wo; dh = Uh; dl = Ul; off = i - 786432; }
        float4 v = ((const float4*)src)[off];
        ushort4 hh, ll;
        split2(v.x, hh.x, ll.x); split2(v.y, hh.y, ll.y);
        split2(v.z, hh.z, ll.z); split2(v.w, hh.w, ll.w);
        ((ushort4*)dh)[off] = hh;
        ((ushort4*)dl)[off] = ll;
    } else {                               // transpose+split query
        int t = bid - 4352;                // 1024 blocks
        int k0 = (t & 15) * 64, s0 = ((t >> 4) & 15) * 64, b = t >> 8;
        const float* src = q + ((size_t)b * 1024 + s0) * 1024 + k0;
        int tr = tid >> 4, tc4 = (tid & 15) * 4;
#pragma unroll
        for (int rs = 0; rs < 4; rs++) {
            int r = rs * 16 + tr;
            float4 v = *(const float4*)&src[(size_t)r * 1024 + tc4];
            T[tc4 + 0][r] = v.x; T[tc4 + 1][r] = v.y;
            T[tc4 + 2][r] = v.z; T[tc4 + 3][r] = v.w;
        }
        __syncthreads();
        unsigned short* dh = qTh + ((size_t)b * 1024 + k0) * 1024 + s0;
        unsigned short* dl = qTl + ((size_t)b * 1024 + k0) * 1024 + s0;
#pragma unroll
        for (int rs = 0; rs < 4; rs++) {
            int kk = rs * 16 + tr;
            ushort4 hh, ll;
            split2(T[kk][tc4 + 0], hh.x, ll.x);
            split2(T[kk][tc4 + 1], hh.y, ll.y);
            split2(T[kk][tc4 + 2], hh.z, ll.z);
            split2(T[kk][tc4 + 3], hh.w, ll.w);
            *(ushort4*)&dh[(size_t)kk * 1024 + tc4] = hh;
            *(ushort4*)&dl[(size_t)kk * 1024 + tc4] = ll;
        }
    }
}

// ---- 64x64-tile split-bf16 MFMA NT GEMM, double-buffered LDS (2-phase) ------
// C[m][n] = sum_k A[m][k]*B[n][k]. KS>1: write fp32 partial at Pf + z*bsC.
// BMODE: 0 none, 1 col-bias b[n], 2 DC-row bias (ks==0 partial only).
template<int KS, int BMODE, bool SPLIT>
__global__ __launch_bounds__(256, 4) void mfma64(
    const unsigned short* __restrict__ Ah, const unsigned short* __restrict__ Al,
    int lda, long bsA,
    const unsigned short* __restrict__ Bh, const unsigned short* __restrict__ Bl,
    int ldb, long bsB,
    float* __restrict__ Cf, unsigned short* __restrict__ Ch, unsigned short* __restrict__ Cl,
    int ldc, long bsC,
    float* __restrict__ Pf, const float* __restrict__ bias, int K)
{
    __shared__ unsigned short smem[2][8192];  // 2 x (Ah|Al|Bh|Bl 64x32 tiles)
    const int tid = threadIdx.x, lane = tid & 63, w = tid >> 6;
    const int wm = w >> 1, wn = w & 1;
    const int m0 = blockIdx.y * 64, n0 = blockIdx.x * 64;
    const int la = lane & 15, kg = lane >> 4;
    int bz, ks;
    if constexpr (KS > 1) { bz = blockIdx.z / KS; ks = blockIdx.z % KS; }
    else                  { bz = blockIdx.z; ks = 0; }
    const int Kc = K / KS;

    const unsigned short* pAh = Ah + (long)bz * bsA + (size_t)(m0 + w * 16 + la) * lda + ks * Kc + kg * 8;
    const unsigned short* pAl = Al + (long)bz * bsA + (size_t)(m0 + w * 16 + la) * lda + ks * Kc + kg * 8;
    const unsigned short* pBh = Bh + (long)bz * bsB + (size_t)(n0 + w * 16 + la) * ldb + ks * Kc + kg * 8;
    const unsigned short* pBl = Bl + (long)bz * bsB + (size_t)(n0 + w * 16 + la) * ldb + ks * Kc + kg * 8;

    // prologue: stage tile 0 into buffer 0
    gload16(pAh, &smem[0][w * 512]);
    gload16(pAl, &smem[0][2048 + w * 512]);
    gload16(pBh, &smem[0][4096 + w * 512]);
    gload16(pBl, &smem[0][6144 + w * 512]);
    pAh += 32; pAl += 32; pBh += 32; pBl += 32;
    __syncthreads();

    f32x4 acc[2][2] = {};
    int cur = 0;
    for (int kt = 0; kt < Kc; kt += 32) {
        if (kt + 32 < Kc) {               // prefetch next tile into other buffer
            int nb = cur ^ 1;
            gload16(pAh, &smem[nb][w * 512]);
            gload16(pAl, &smem[nb][2048 + w * 512]);
            gload16(pBh, &smem[nb][4096 + w * 512]);
            gload16(pBl, &smem[nb][6144 + w * 512]);
            pAh += 32; pAl += 32; pBh += 32; pBl += 32;
        }
        bf16x8 fah[2], fal[2], fbh[2], fbl[2];
#pragma unroll
        for (int i = 0; i < 2; i++) {
            fah[i] = *reinterpret_cast<const bf16x8*>(&smem[cur][(wm * 2 + i) * 512 + lane * 8]);
            fal[i] = *reinterpret_cast<const bf16x8*>(&smem[cur][2048 + (wm * 2 + i) * 512 + lane * 8]);
            fbh[i] = *reinterpret_cast<const bf16x8*>(&smem[cur][4096 + (wn * 2 + i) * 512 + lane * 8]);
            fbl[i] = *reinterpret_cast<const bf16x8*>(&smem[cur][6144 + (wn * 2 + i) * 512 + lane * 8]);
        }
#pragma unroll
        for (int j = 0; j < 2; j++)
#pragma unroll
            for (int i = 0; i < 2; i++) {
                acc[i][j] = __builtin_amdgcn_mfma_f32_16x16x32_bf16(fah[i], fbh[j], acc[i][j], 0, 0, 0);
                acc[i][j] = __builtin_amdgcn_mfma_f32_16x16x32_bf16(fal[i], fbh[j], acc[i][j], 0, 0, 0);
                acc[i][j] = __builtin_amdgcn_mfma_f32_16x16x32_bf16(fah[i], fbl[j], acc[i][j], 0, 0, 0);
            }
        __syncthreads();                  // drains prefetch; frees cur for reuse
        cur ^= 1;
    }

    const int r0 = (lane >> 4) * 4, cl = lane & 15;
    if constexpr (KS > 1) {
        const int N = gridDim.x * 64;
        float* Pb = Pf + (long)blockIdx.z * bsC;
#pragma unroll
        for (int i = 0; i < 2; i++)
#pragma unroll
            for (int j = 0; j < 2; j++) {
                int gr0 = m0 + wm * 32 + i * 16 + r0;
                int gc  = n0 + wn * 32 + j * 16 + cl;
#pragma unroll
                for (int r = 0; r < 4; r++) {
                    int gr = gr0 + r;
                    float v = acc[i][j][r];
                    if (BMODE == 2 && ks == 0 && (gr & 127) == 0)
                        v += 1024.0f * bias[gc];
                    Pb[(long)gr * N + gc] = v;
                }
            }
    } else {
        float* Cfb = Cf ? Cf + (long)bz * bsC : nullptr;
        unsigned short* Chb = Ch ? Ch + (long)bz * bsC : nullptr;
        unsigned short* Clb = Cl ? Cl + (long)bz * bsC : nullptr;
#pragma unroll
        for (int i = 0; i < 2; i++)
#pragma unroll
            for (int j = 0; j < 2; j++) {
                int gr0 = m0 + wm * 32 + i * 16 + r0;
                int gc  = n0 + wn * 32 + j * 16 + cl;
                float bn = (BMODE == 1) ? bias[gc] : 0.f;
#pragma unroll
                for (int r = 0; r < 4; r++) {
                    int gr = gr0 + r;
                    float v = acc[i][j][r] + bn;
                    if (BMODE == 2 && (gr & 127) == 0) v += 1024.0f * bias[gc];
                    size_t o = (size_t)gr * ldc + gc;
                    if (SPLIT) {
                        unsigned short hh, ll; split2(v, hh, ll);
                        Chb[o] = hh; Clb[o] = ll;
                    } else {
                        Cfb[o] = v;
                    }
                }
            }
    }
}

// ---- split-K reduce + epilogue (float4, pow2 slice strides via shifts) ------
template<int KS, bool SPLIT>
__global__ void reduce_k(const float* __restrict__ P,
                         float* __restrict__ Cf,
                         unsigned short* __restrict__ Ch, unsigned short* __restrict__ Cl,
                         int mn4bits, int total4)
{
    int e = blockIdx.x * 256 + threadIdx.x;
    if (e >= total4) return;
    int bz = e >> mn4bits, rem = e & ((1 << mn4bits) - 1);
    const float4* P4 = (const float4*)P;
    float4 s = P4[((long)(bz * KS) << mn4bits) + rem];
#pragma unroll
    for (int k = 1; k < KS; k++) {
        float4 t = P4[((long)(bz * KS + k) << mn4bits) + rem];
        s.x += t.x; s.y += t.y; s.z += t.z; s.w += t.w;
    }
    long o4 = ((long)bz << mn4bits) + rem;
    if (SPLIT) {
        ushort4 hh, ll;
        split2(s.x, hh.x, ll.x); split2(s.y, hh.y, ll.y);
        split2(s.z, hh.z, ll.z); split2(s.w, hh.w, ll.w);
        ((ushort4*)Ch)[o4] = hh;
        ((ushort4*)Cl)[o4] = ll;
    } else {
        ((float4*)Cf)[o4] = s;
    }
}

// ---- scores (fp32) + 1024-wide softmax -> attn[bh][64] -----------------------
__global__ void score_k(const float* __restrict__ QF,
                        const float* __restrict__ fq, const float* __restrict__ fk,
                        float* __restrict__ attnW) {
    int bh = blockIdx.x, b = bh >> 4, h = bh & 15;
    const float* QFb = QF + (size_t)b * 393216;     // [128 f2][3072 ch]
    const float* wq = fq + (size_t)h * 4096;
    const float* wk = fk + (size_t)h * 4096;
    __shared__ float red[256];
    int tid = threadIdx.x;
    int f = tid & 63, dg = tid >> 6;
    int cq = h * 64;
    float p = 0.f;
#pragma unroll
    for (int i = 0; i < 16; i++) {
        int d = dg * 16 + i;
        float w2 = wq[f * 64 + d] * wk[f * 64 + d];
        p += w2 * (QFb[(2 * f) * 3072 + cq + d]     * QFb[(2 * f) * 3072 + 1024 + cq + d]
                 + QFb[(2 * f + 1) * 3072 + cq + d] * QFb[(2 * f + 1) * 3072 + 1024 + cq + d]);
    }
    red[tid] = p;
    __syncthreads();
    if (tid < 64) {
        float s = red[tid] + red[tid + 64] + red[tid + 128] + red[tid + 192];
        float mx = s;
        for (int m = 1; m < 64; m <<= 1) mx = fmaxf(mx, __shfl_xor(mx, m));
        mx = fmaxf(mx, 0.0f);                   // padded zero scores join the max
        float e = expf(s - mx);
        float sum = e;
        for (int m = 1; m < 64; m <<= 1) sum += __shfl_xor(sum, m);
        sum += 960.0f * expf(-mx);              // the S-M zero-score entries
        attnW[bh * 64 + tid] = e / sum;
    }
}

// ---- OVW[b][f2][ch] = attn*wv*vf, split hi/lo (float4-wide elementwise) -----
__global__ void ov_k(const float* __restrict__ QF, const float* __restrict__ attnW,
                     const float* __restrict__ fv,
                     unsigned short* __restrict__ OVWh, unsigned short* __restrict__ OVWl) {
    int e = blockIdx.x * 256 + threadIdx.x;     // 131072 float4 = [4][128][1024]
    int b = e >> 15, rem = e & 32767;
    int f2 = rem >> 8, c4 = rem & 255;
    int ch = c4 * 4, h = ch >> 6, d = ch & 63;
    float4 v = *(const float4*)&QF[(size_t)(b * 128 + f2) * 3072 + 2048 + ch];
    float a = attnW[(b * 16 + h) * 64 + (f2 >> 1)];
    const float4 wvv = *(const float4*)&fv[h * 4096 + (f2 >> 1) * 64 + d];
    ushort4 hh, ll;
    split2(a * wvv.x * v.x, hh.x, ll.x);
    split2(a * wvv.y * v.y, hh.y, ll.y);
    split2(a * wvv.z * v.z, hh.z, ll.z);
    split2(a * wvv.w * v.w, hh.w, ll.w);
    long o4 = ((long)(b * 128 + f2) * 1024 + ch) >> 2;
    ((ushort4*)OVWh)[o4] = hh;
    ((ushort4*)OVWl)[o4] = ll;
}

extern "C" void kernel_launch(void* const* d_in, const int* in_sizes, int n_in,
                              void* d_out, int out_size, void* d_ws, size_t ws_size,
                              hipStream_t stream) {
    const float* query  = (const float*)d_in[0];
    const float* w_qkv  = (const float*)d_in[1];
    const float* b_qkv  = (const float*)d_in[2];
    const float* w_out  = (const float*)d_in[3];
    const float* b_out  = (const float*)d_in[4];
    const float* freq_q = (const float*)d_in[5];
    const float* freq_k = (const float*)d_in[6];
    const float* freq_v = (const float*)d_in[7];

    char* W = (char*)d_ws;
    unsigned short* qTh  = (unsigned short*)(W);                  // [4][1024][1024]
    unsigned short* qTl  = (unsigned short*)(W + 8388608);
    unsigned short* Wh   = (unsigned short*)(W + 16777216);       // [3072][1024]
    unsigned short* Wl   = (unsigned short*)(W + 23068672);
    unsigned short* Uh   = (unsigned short*)(W + 29360128);       // [1024][1024]
    unsigned short* Ul   = (unsigned short*)(W + 31457280);
    unsigned short* TWFh = (unsigned short*)(W + 33554432);       // [128][1024]
    unsigned short* TWFl = (unsigned short*)(W + 33816576);
    unsigned short* TWIh = (unsigned short*)(W + 34078720);       // [1024][128]
    unsigned short* TWIl = (unsigned short*)(W + 34340864);
    unsigned short* TWQh = (unsigned short*)(W + 34603008);       // [4][128][1024]
    unsigned short* TWQl = (unsigned short*)(W + 35651584);
    float*          QF   = (float*)        (W + 36700160);        // [512][3072] fp32
    unsigned short* OVWh = (unsigned short*)(W + 42991616);       // [4][128][1024]
    unsigned short* OVWl = (unsigned short*)(W + 44040192);
    unsigned short* POVh = (unsigned short*)(W + 45088768);       // [4][1024][128]
    unsigned short* POVl = (unsigned short*)(W + 46137344);
    float*          attnW= (float*)        (W + 47185920);        // [64][64]
    float*          P_A  = (float*)        (W + 47202304);        // [16][2^17] floats
    float*          P_C  = (float*)        (W + 55590912);        // [16][2^17] floats
    float*          P_B  = (float*)        (W + 63979520);        // [2][2^21] floats
                                                                  // end 80756736 B

    prep<<<5376, 256, 0, stream>>>(query, w_qkv, w_out, qTh, qTl, Wh, Wl, Uh, Ul,
                                   TWFh, TWFl, TWIh, TWIl);

    // A: TWQ[b][f2][k] = sum_s TWF[f2][s]*qT[b][k][s]   (split-K=4 -> partials)
    mfma64<4, 0, false><<<dim3(16, 2, 16), 256, 0, stream>>>(
        TWFh, TWFl, 1024, 0, qTh, qTl, 1024, 1048576,
        nullptr, nullptr, nullptr, 0, 131072, P_A, nullptr, 1024);
    reduce_k<4, true><<<512, 256, 0, stream>>>(P_A, nullptr, TWQh, TWQl, 15, 131072);

    // B: QF[(b,f2)][c] = sum_k TWQ[(b,f2)][k]*w_qkv[c][k]  (split-K=2,
    //    +1024*b_qkv at DC rows folded into ks==0 partial)
    mfma64<2, 2, false><<<dim3(48, 8, 2), 256, 0, stream>>>(
        TWQh, TWQl, 1024, 0, Wh, Wl, 1024, 0,
        nullptr, nullptr, nullptr, 0, 2097152, P_B, b_qkv, 1024);
    reduce_k<2, false><<<1536, 256, 0, stream>>>(P_B, QF, nullptr, nullptr, 19, 393216);

    // scores -> softmax(1024-wide) -> attn ; then OVW = attn*wv*vf (split)
    score_k<<<64, 256, 0, stream>>>(QF, freq_q, freq_k, attnW);
    ov_k<<<512, 256, 0, stream>>>(QF, attnW, freq_v, OVWh, OVWl);

    // C: POV[b][n][f2] = sum_ch w_out[n][ch]*OVW[b][f2][ch]  (split-K=4)
    mfma64<4, 0, false><<<dim3(2, 16, 16), 256, 0, stream>>>(
        Uh, Ul, 1024, 0, OVWh, OVWl, 1024, 131072,
        nullptr, nullptr, nullptr, 0, 131072, P_C, nullptr, 1024);
    reduce_k<4, true><<<512, 256, 0, stream>>>(P_C, nullptr, POVh, POVl, 15, 131072);

    // D: d_out[b][s][n] = sum_f2 TWI[s][f2]*POV[b][n][f2] + b_out[n]
    mfma64<1, 1, false><<<dim3(16, 16, 4), 256, 0, stream>>>(
        TWIh, TWIl, 128, 0, POVh, POVl, 128, 131072,
        (float*)d_out, nullptr, nullptr, 1024, 1048576, nullptr, b_out, 128);
}

// Round 13
// 85.993 us; speedup vs baseline: 1.3880x; 1.1220x over previous
//
#include <hip/hip_runtime.h>
#include <math.h>

// FrequencyAttention: QF = (TWF.qT).W^T ; d_out = TWI.(U.OVW^T)^T + b_out.
// Split-bf16 MFMA (hi/lo, 3-term) on 64x64 tiles; split-K + fp32 reduce.
// R13: w_qkv/w_out consumed fp32 with split-on-staging (reg->LDS, off the
// fragment path); score fused into reduce_B; prep shrinks to twiddles+qT.

typedef __bf16 bf16x8 __attribute__((ext_vector_type(8)));
typedef float  f32x4  __attribute__((ext_vector_type(4)));

__device__ __forceinline__ unsigned short f2bf(float x) {
    unsigned u = __builtin_bit_cast(unsigned, x);
    u = (u + 0x7fffu + ((u >> 16) & 1u)) >> 16;   // RTN-even
    return (unsigned short)u;
}
__device__ __forceinline__ float bf2f(unsigned short h) {
    return __builtin_bit_cast(float, ((unsigned)h) << 16);
}
__device__ __forceinline__ void split2(float x, unsigned short& h, unsigned short& l) {
    h = f2bf(x);
    l = f2bf(x - bf2f(h));
}
// split 8 fp32 -> bf16 hi/lo and store 16B each to LDS
__device__ __forceinline__ void splitst(const float4& a0, const float4& a1,
                                        unsigned short* dsth, unsigned short* dstl) {
    float v[8] = {a0.x, a0.y, a0.z, a0.w, a1.x, a1.y, a1.z, a1.w};
    bf16x8 hv, lv;
#pragma unroll
    for (int j = 0; j < 8; j++) {
        unsigned short h, l; split2(v[j], h, l);
        hv[j] = __builtin_bit_cast(__bf16, h);
        lv[j] = __builtin_bit_cast(__bf16, l);
    }
    *reinterpret_cast<bf16x8*>(dsth) = hv;
    *reinterpret_cast<bf16x8*>(dstl) = lv;
}

__device__ __forceinline__ void gload16(const void* g, void* l) {
    __builtin_amdgcn_global_load_lds(
        (const __attribute__((address_space(1))) unsigned int*)g,
        (__attribute__((address_space(3))) unsigned int*)l,
        16, 0, 0);
}

// ---- prep: twiddles + query transpose/split ---------------------------------
__global__ __launch_bounds__(256) void prep(
    const float* __restrict__ q,
    unsigned short* __restrict__ qTh, unsigned short* __restrict__ qTl,
    unsigned short* __restrict__ TWFh, unsigned short* __restrict__ TWFl,
    unsigned short* __restrict__ TWIh, unsigned short* __restrict__ TWIl)
{
    __shared__ float T[64][65];
    int bid = blockIdx.x, tid = threadIdx.x;
    if (bid < 256) {                       // twiddles: 65536 = 64f x 1024s
        int idx = bid * 256 + tid;
        int f = idx >> 10, s = idx & 1023;
        float th = (float)((f * s) & 1023) * (6.283185307179586f / 1024.0f);
        float sn, c;
        sincosf(th, &sn, &c);
        unsigned short ch, cl, sh, sl;
        split2(c, ch, cl); split2(sn, sh, sl);
        TWFh[(2 * f) * 1024 + s] = ch;     TWFl[(2 * f) * 1024 + s] = cl;
        TWFh[(2 * f + 1) * 1024 + s] = sh; TWFl[(2 * f + 1) * 1024 + s] = sl;
        TWIh[s * 128 + 2 * f] = ch;        TWIl[s * 128 + 2 * f] = cl;
        TWIh[s * 128 + 2 * f + 1] = sh;    TWIl[s * 128 + 2 * f + 1] = sl;
    } else {                               // transpose+split query, 1024 blocks
        int t = bid - 256;
        int k0 = (t & 15) * 64, s0 = ((t >> 4) & 15) * 64, b = t >> 8;
        const float* src = q + ((size_t)b * 1024 + s0) * 1024 + k0;
        int tr = tid >> 4, tc4 = (tid & 15) * 4;
#pragma unroll
        for (int rs = 0; rs < 4; rs++) {
            int r = rs * 16 + tr;
            float4 v = *(const float4*)&src[(size_t)r * 1024 + tc4];
            T[tc4 + 0][r] = v.x; T[tc4 + 1][r] = v.y;
            T[tc4 + 2][r] = v.z; T[tc4 + 3][r] = v.w;
        }
        __syncthreads();
        unsigned short* dh = qTh + ((size_t)b * 1024 + k0) * 1024 + s0;
        unsigned short* dl = qTl + ((size_t)b * 1024 + k0) * 1024 + s0;
#pragma unroll
        for (int rs = 0; rs < 4; rs++) {
            int kk = rs * 16 + tr;
            ushort4 hh, ll;
            split2(T[kk][tc4 + 0], hh.x, ll.x);
            split2(T[kk][tc4 + 1], hh.y, ll.y);
            split2(T[kk][tc4 + 2], hh.z, ll.z);
            split2(T[kk][tc4 + 3], hh.w, ll.w);
            *(ushort4*)&dh[(size_t)kk * 1024 + tc4] = hh;
            *(ushort4*)&dl[(size_t)kk * 1024 + tc4] = ll;
        }
    }
}

// ---- 64x64-tile split-bf16 MFMA NT GEMM, dbuf LDS; fp32 operands staged -----
// ASTG/BSTG: operand comes as fp32, split to hi/lo during staging (reg->LDS).
// KS>1: fp32 partial at Pf + z*bsC. BMODE: 0 none, 1 col-bias, 2 DC-row bias
// (+1024*b[n] where (row&127)==0; partials: only at ks==0).
template<int KS, int BMODE, bool ASTG, bool BSTG>
__global__ __launch_bounds__(256, 4) void mfma64(
    const unsigned short* __restrict__ Ah, const unsigned short* __restrict__ Al,
    const float* __restrict__ Af32, int lda, long bsA,
    const unsigned short* __restrict__ Bh, const unsigned short* __restrict__ Bl,
    const float* __restrict__ Bf32, int ldb, long bsB,
    float* __restrict__ Cf, int ldc, long bsC,
    float* __restrict__ Pf, const float* __restrict__ bias, int K)
{
    __shared__ unsigned short smem[2][8192];  // 2 x (Ah|Al|Bh|Bl 64x32 tiles)
    const int tid = threadIdx.x, lane = tid & 63, w = tid >> 6;
    const int wm = w >> 1, wn = w & 1;
    const int m0 = blockIdx.y * 64, n0 = blockIdx.x * 64;
    const int la = lane & 15, kg = lane >> 4;
    int bz, ks;
    if constexpr (KS > 1) { bz = blockIdx.z / KS; ks = blockIdx.z % KS; }
    else                  { bz = blockIdx.z; ks = 0; }
    const int Kc = K / KS;

    const unsigned short *pAh = nullptr, *pAl = nullptr, *pBh = nullptr, *pBl = nullptr;
    const float *pA32 = nullptr, *pB32 = nullptr;
    if constexpr (!ASTG) {
        pAh = Ah + (long)bz * bsA + (size_t)(m0 + w * 16 + la) * lda + ks * Kc + kg * 8;
        pAl = Al + (long)bz * bsA + (size_t)(m0 + w * 16 + la) * lda + ks * Kc + kg * 8;
    } else {
        pA32 = Af32 + (long)bz * bsA + (size_t)(m0 + w * 16 + la) * lda + ks * Kc + kg * 8;
    }
    if constexpr (!BSTG) {
        pBh = Bh + (long)bz * bsB + (size_t)(n0 + w * 16 + la) * ldb + ks * Kc + kg * 8;
        pBl = Bl + (long)bz * bsB + (size_t)(n0 + w * 16 + la) * ldb + ks * Kc + kg * 8;
    } else {
        pB32 = Bf32 + (long)bz * bsB + (size_t)(n0 + w * 16 + la) * ldb + ks * Kc + kg * 8;
    }

    // prologue: stage tile 0 into buffer 0
    if constexpr (!ASTG) {
        gload16(pAh, &smem[0][w * 512]); gload16(pAl, &smem[0][2048 + w * 512]);
        pAh += 32; pAl += 32;
    } else {
        float4 a0 = *(const float4*)pA32, a1 = *(const float4*)(pA32 + 4); pA32 += 32;
        splitst(a0, a1, &smem[0][w * 512 + lane * 8], &smem[0][2048 + w * 512 + lane * 8]);
    }
    if constexpr (!BSTG) {
        gload16(pBh, &smem[0][4096 + w * 512]); gload16(pBl, &smem[0][6144 + w * 512]);
        pBh += 32; pBl += 32;
    } else {
        float4 b0 = *(const float4*)pB32, b1 = *(const float4*)(pB32 + 4); pB32 += 32;
        splitst(b0, b1, &smem[0][4096 + w * 512 + lane * 8], &smem[0][6144 + w * 512 + lane * 8]);
    }
    __syncthreads();

    f32x4 acc[2][2] = {};
    int cur = 0;
    for (int kt = 0; kt < Kc; kt += 32) {
        const bool hn = (kt + 32 < Kc);
        float4 na0, na1, nb0, nb1;
        if (hn) {                          // issue next-tile loads BEFORE compute
            int nb = cur ^ 1;
            if constexpr (!ASTG) {
                gload16(pAh, &smem[nb][w * 512]); gload16(pAl, &smem[nb][2048 + w * 512]);
                pAh += 32; pAl += 32;
            } else {
                na0 = *(const float4*)pA32; na1 = *(const float4*)(pA32 + 4); pA32 += 32;
            }
            if constexpr (!BSTG) {
                gload16(pBh, &smem[nb][4096 + w * 512]); gload16(pBl, &smem[nb][6144 + w * 512]);
                pBh += 32; pBl += 32;
            } else {
                nb0 = *(const float4*)pB32; nb1 = *(const float4*)(pB32 + 4); pB32 += 32;
            }
        }
        bf16x8 fah[2], fal[2], fbh[2], fbl[2];
#pragma unroll
        for (int i = 0; i < 2; i++) {
            fah[i] = *reinterpret_cast<const bf16x8*>(&smem[cur][(wm * 2 + i) * 512 + lane * 8]);
            fal[i] = *reinterpret_cast<const bf16x8*>(&smem[cur][2048 + (wm * 2 + i) * 512 + lane * 8]);
            fbh[i] = *reinterpret_cast<const bf16x8*>(&smem[cur][4096 + (wn * 2 + i) * 512 + lane * 8]);
            fbl[i] = *reinterpret_cast<const bf16x8*>(&smem[cur][6144 + (wn * 2 + i) * 512 + lane * 8]);
        }
#pragma unroll
        for (int j = 0; j < 2; j++)
#pragma unroll
            for (int i = 0; i < 2; i++) {
                acc[i][j] = __builtin_amdgcn_mfma_f32_16x16x32_bf16(fah[i], fbh[j], acc[i][j], 0, 0, 0);
                acc[i][j] = __builtin_amdgcn_mfma_f32_16x16x32_bf16(fal[i], fbh[j], acc[i][j], 0, 0, 0);
                acc[i][j] = __builtin_amdgcn_mfma_f32_16x16x32_bf16(fah[i], fbl[j], acc[i][j], 0, 0, 0);
            }
        if (hn) {                          // split+write after compute, pre-barrier
            int nb = cur ^ 1;
            if constexpr (ASTG)
                splitst(na0, na1, &smem[nb][w * 512 + lane * 8], &smem[nb][2048 + w * 512 + lane * 8]);
            if constexpr (BSTG)
                splitst(nb0, nb1, &smem[nb][4096 + w * 512 + lane * 8], &smem[nb][6144 + w * 512 + lane * 8]);
        }
        __syncthreads();
        cur ^= 1;
    }

    const int r0 = (lane >> 4) * 4, cl = lane & 15;
    if constexpr (KS > 1) {
        const int N = gridDim.x * 64;
        float* Pb = Pf + (long)blockIdx.z * bsC;
#pragma unroll
        for (int i = 0; i < 2; i++)
#pragma unroll
            for (int j = 0; j < 2; j++) {
                int gr0 = m0 + wm * 32 + i * 16 + r0;
                int gc  = n0 + wn * 32 + j * 16 + cl;
#pragma unroll
                for (int r = 0; r < 4; r++) {
                    int gr = gr0 + r;
                    float v = acc[i][j][r];
                    if (BMODE == 2 && ks == 0 && (gr & 127) == 0)
                        v += 1024.0f * bias[gc];
                    Pb[(long)gr * N + gc] = v;
                }
            }
    } else {
        float* Cfb = Cf + (long)bz * bsC;
#pragma unroll
        for (int i = 0; i < 2; i++)
#pragma unroll
            for (int j = 0; j < 2; j++) {
                int gr0 = m0 + wm * 32 + i * 16 + r0;
                int gc  = n0 + wn * 32 + j * 16 + cl;
                float bn = (BMODE == 1) ? bias[gc] : 0.f;
#pragma unroll
                for (int r = 0; r < 4; r++) {
                    int gr = gr0 + r;
                    float v = acc[i][j][r] + bn;
                    if (BMODE == 2 && (gr & 127) == 0) v += 1024.0f * bias[gc];
                    Cfb[(size_t)gr * ldc + gc] = v;
                }
            }
    }
}

// ---- split-K reduce -> bf16 hi/lo (for GEMMs A and C) -----------------------
template<int KS>
__global__ void reduce_k(const float* __restrict__ P,
                         unsigned short* __restrict__ Ch, unsigned short* __restrict__ Cl,
                         int mn4bits, int total4)
{
    int e = blockIdx.x * 256 + threadIdx.x;
    if (e >= total4) return;
    int bz = e >> mn4bits, rem = e & ((1 << mn4bits) - 1);
    const float4* P4 = (const float4*)P;
    float4 s = P4[((long)(bz * KS) << mn4bits) + rem];
#pragma unroll
    for (int k = 1; k < KS; k++) {
        float4 t = P4[((long)(bz * KS + k) << mn4bits) + rem];
        s.x += t.x; s.y += t.y; s.z += t.z; s.w += t.w;
    }
    long o4 = ((long)bz << mn4bits) + rem;
    ushort4 hh, ll;
    split2(s.x, hh.x, ll.x); split2(s.y, hh.y, ll.y);
    split2(s.z, hh.z, ll.z); split2(s.w, hh.w, ll.w);
    ((ushort4*)Ch)[o4] = hh;
    ((ushort4*)Cl)[o4] = ll;
}

// ---- reduce_B (KS=2) + fused raw scores: block per (b,f) --------------------
// Sums the two P_B partials into QF rows (2f, 2f+1) and computes
// scoreRaw[(b*16+h)*64+f] = sum_d wq*wk*(qr*kr + qi*ki).
__global__ __launch_bounds__(256) void redB_score(
    const float* __restrict__ P, const float* __restrict__ fq,
    const float* __restrict__ fk, float* __restrict__ QF,
    float* __restrict__ scoreRaw)
{
    int bid = blockIdx.x, tid = threadIdx.x;
    int b = bid >> 6, f = bid & 63;
    const long r4 = ((long)(b * 128 + 2 * f) * 3072) >> 2;   // float4 idx of row 2f
    const float4* P0 = (const float4*)P;
    const float4* P1 = (const float4*)P + 524288;            // + 2^21 floats
    float4* QF4 = (float4*)QF;
    // phase 1: QF rows (1536 float4, two adjacent rows)
    for (int i = tid; i < 1536; i += 256) {
        long o = r4 + i;
        float4 x = P0[o], y = P1[o];
        x.x += y.x; x.y += y.y; x.z += y.z; x.w += y.w;
        QF4[o] = x;
    }
    // phase 2: score partials; thread = (h, slot)
    __shared__ float red[256];
    int h = tid >> 4, s = tid & 15, rsel = s >> 3, j = s & 7;
    long rowb = r4 + (long)rsel * 768;
    float acc = 0.f;
#pragma unroll
    for (int t = 0; t < 2; t++) {
        int qc = h * 16 + j * 2 + t;
        float4 qv = P0[rowb + qc], q1 = P1[rowb + qc];
        float4 kv = P0[rowb + qc + 256], k1 = P1[rowb + qc + 256];
        qv.x += q1.x; qv.y += q1.y; qv.z += q1.z; qv.w += q1.w;
        kv.x += k1.x; kv.y += k1.y; kv.z += k1.z; kv.w += k1.w;
        const float4 wq = *(const float4*)&fq[h * 4096 + f * 64 + (qc & 15) * 4];
        const float4 wk = *(const float4*)&fk[h * 4096 + f * 64 + (qc & 15) * 4];
        acc += wq.x * wk.x * qv.x * kv.x + wq.y * wk.y * qv.y * kv.y
             + wq.z * wk.z * qv.z * kv.z + wq.w * wk.w * qv.w * kv.w;
    }
    red[tid] = acc;
    __syncthreads();
    if (tid < 16) {
        float ssum = 0.f;
#pragma unroll
        for (int u = 0; u < 16; u++) ssum += red[tid * 16 + u];
        scoreRaw[(b * 16 + tid) * 64 + f] = ssum;
    }
}

// ---- softmax over 64 freqs (1024-wide: 960 zero-score entries included) -----
__global__ void softmax_k(const float* __restrict__ sr, float* __restrict__ attnW) {
    int bh = blockIdx.x, f = threadIdx.x;     // 64 threads = 1 wave
    float s = sr[bh * 64 + f];
    float mx = s;
    for (int m = 1; m < 64; m <<= 1) mx = fmaxf(mx, __shfl_xor(mx, m));
    mx = fmaxf(mx, 0.0f);
    float e = expf(s - mx);
    float sum = e;
    for (int m = 1; m < 64; m <<= 1) sum += __shfl_xor(sum, m);
    sum += 960.0f * expf(-mx);
    attnW[bh * 64 + f] = e / sum;
}

// ---- OVW[b][f2][ch] = attn*wv*vf, split hi/lo (float4-wide elementwise) -----
__global__ void ov_k(const float* __restrict__ QF, const float* __restrict__ attnW,
                     const float* __restrict__ fv,
                     unsigned short* __restrict__ OVWh, unsigned short* __restrict__ OVWl) {
    int e = blockIdx.x * 256 + threadIdx.x;     // 131072 float4 = [4][128][1024]
    int b = e >> 15, rem = e & 32767;
    int f2 = rem >> 8, c4 = rem & 255;
    int ch = c4 * 4, h = ch >> 6, d = ch & 63;
    float4 v = *(const float4*)&QF[(size_t)(b * 128 + f2) * 3072 + 2048 + ch];
    float a = attnW[(b * 16 + h) * 64 + (f2 >> 1)];
    const float4 wvv = *(const float4*)&fv[h * 4096 + (f2 >> 1) * 64 + d];
    ushort4 hh, ll;
    split2(a * wvv.x * v.x, hh.x, ll.x);
    split2(a * wvv.y * v.y, hh.y, ll.y);
    split2(a * wvv.z * v.z, hh.z, ll.z);
    split2(a * wvv.w * v.w, hh.w, ll.w);
    long o4 = ((long)(b * 128 + f2) * 1024 + ch) >> 2;
    ((ushort4*)OVWh)[o4] = hh;
    ((ushort4*)OVWl)[o4] = ll;
}

extern "C" void kernel_launch(void* const* d_in, const int* in_sizes, int n_in,
                              void* d_out, int out_size, void* d_ws, size_t ws_size,
                              hipStream_t stream) {
    const float* query  = (const float*)d_in[0];
    const float* w_qkv  = (const float*)d_in[1];
    const float* b_qkv  = (const float*)d_in[2];
    const float* w_out  = (const float*)d_in[3];
    const float* b_out  = (const float*)d_in[4];
    const float* freq_q = (const float*)d_in[5];
    const float* freq_k = (const float*)d_in[6];
    const float* freq_v = (const float*)d_in[7];

    char* W = (char*)d_ws;
    unsigned short* qTh   = (unsigned short*)(W);                 // [4][1024][1024]
    unsigned short* qTl   = (unsigned short*)(W + 8388608);
    unsigned short* TWFh  = (unsigned short*)(W + 16777216);      // [128][1024]
    unsigned short* TWFl  = (unsigned short*)(W + 17039360);
    unsigned short* TWIh  = (unsigned short*)(W + 17301504);      // [1024][128]
    unsigned short* TWIl  = (unsigned short*)(W + 17563648);
    unsigned short* TWQh  = (unsigned short*)(W + 17825792);      // [512][1024]
    unsigned short* TWQl  = (unsigned short*)(W + 18874368);
    float*          QF    = (float*)        (W + 19922944);       // [512][3072] fp32
    unsigned short* OVWh  = (unsigned short*)(W + 26214400);      // [4][128][1024]
    unsigned short* OVWl  = (unsigned short*)(W + 27262976);
    unsigned short* POVh  = (unsigned short*)(W + 28311552);      // [4][1024][128]
    unsigned short* POVl  = (unsigned short*)(W + 29360128);
    float*          attnW = (float*)        (W + 30408704);       // [64][64]
    float*          scoreR= (float*)        (W + 30425088);       // [64][64]
    float*          P_A   = (float*)        (W + 30441472);       // [16][2^17] floats
    float*          P_C   = (float*)        (W + 38830080);       // [16][2^17] floats
    float*          P_B   = (float*)        (W + 47218688);       // [2][2^21] floats
                                                                  // end 63995904 B

    prep<<<1280, 256, 0, stream>>>(query, qTh, qTl, TWFh, TWFl, TWIh, TWIl);

    // A: TWQ[(b,f2)][k] = sum_s TWF[f2][s]*qT[b][k][s]   (split-K=4)
    mfma64<4, 0, false, false><<<dim3(16, 2, 16), 256, 0, stream>>>(
        TWFh, TWFl, nullptr, 1024, 0, qTh, qTl, nullptr, 1024, 1048576,
        nullptr, 0, 131072, P_A, nullptr, 1024);
    reduce_k<4><<<512, 256, 0, stream>>>(P_A, TWQh, TWQl, 15, 131072);

    // B: QF[(b,f2)][c] = sum_k TWQ[(b,f2)][k]*w_qkv[c][k]  (split-K=2, w fp32
    //    staged-split; +1024*b_qkv at DC rows folded into ks==0 partial)
    mfma64<2, 2, false, true><<<dim3(48, 8, 2), 256, 0, stream>>>(
        TWQh, TWQl, nullptr, 1024, 0, nullptr, nullptr, w_qkv, 1024, 0,
        nullptr, 0, 2097152, P_B, b_qkv, 1024);

    // reduce B partials -> QF, fused raw scores; then tiny softmax
    redB_score<<<256, 256, 0, stream>>>(P_B, freq_q, freq_k, QF, scoreR);
    softmax_k<<<64, 64, 0, stream>>>(scoreR, attnW);

    // OVW = attn*wv*vf (split)
    ov_k<<<512, 256, 0, stream>>>(QF, attnW, freq_v, OVWh, OVWl);

    // C: POV[b][n][f2] = sum_ch w_out[n][ch]*OVW[b][f2][ch]  (split-K=4,
    //    w_out fp32 staged-split on A side)
    mfma64<4, 0, true, false><<<dim3(2, 16, 16), 256, 0, stream>>>(
        nullptr, nullptr, w_out, 1024, 0, OVWh, OVWl, nullptr, 1024, 131072,
        nullptr, 0, 131072, P_C, nullptr, 1024);
    reduce_k<4><<<512, 256, 0, stream>>>(P_C, POVh, POVl, 15, 131072);

    // D: d_out[b][s][n] = sum_f2 TWI[s][f2]*POV[b][n][f2] + b_out[n]
    mfma64<1, 1, false, false><<<dim3(16, 16, 4), 256, 0, stream>>>(
        TWIh, TWIl, nullptr, 128, 0, POVh, POVl, nullptr, 128, 131072,
        (float*)d_out, 1024, 1048576, nullptr, b_out, 128);
}